// Round 3
// baseline (2509.106 us; speedup 1.0000x reference)
//
#include <hip/hip_runtime.h>
#include <math.h>

// TfLSTM: x[512,256,128] -> LSTM(100, relu) -> LSTM(128, relu, last) -> Dense(19) -> softmax
// Round 3: round-2 split design refitted to ws_size = 256 MiB (measured round 2:
// harness fill poisons exactly 262144 KB). Layer-2 zx is computed in TWO time
// chunks of 128 steps, each reusing zx1's buffer region (dead after rec1);
// LSTM-2 state (c,h) carried between chunk kernels in workspace.
//   ws layout (floats):
//     zxbuf  [0 .. 52428800)            209.7 MB  (zx1 full / zx2 chunk)
//     h1seq  [52428800 .. 65536000)      52.4 MB
//     cbuf   [65536000 .. 65601536)       0.26 MB
//     hbuf   [65601536 .. 65667072)       0.26 MB
//     h2buf  [65667072 .. 65732608)       0.26 MB   total 262.93 MB <= 268.4 MB

#define T_SEQ 256
#define BATCH 512
#define IN_DIM 128
#define H1 100
#define H2 128
#define NCLS 19

__device__ __forceinline__ float sigmoidf_(float x) {
    return 1.0f / (1.0f + __expf(-x));
}

// =================== projection GEMM ===================
// out[orow][n] = bias[n] + sum_k A[r][k] * W[k][n]
// r = blockIdx.x*128 + local row; orow = SWAP ? (r&255)*512 + (r>>8) : r.
// Tile 128x128, micro 8x8, k-chunks of 32, LDS-transposed A.
template<int K, int N, bool SWAP>
__global__ __launch_bounds__(256, 2)
void proj_kernel(const float* __restrict__ A, const float* __restrict__ W,
                 const float* __restrict__ bias, float* __restrict__ out)
{
    constexpr int LD = 132;  // padded LDS stride
    __shared__ __align__(16) float As[32 * LD];  // [k][row]
    __shared__ __align__(16) float Ws[32 * LD];  // [k][col]
    const int tid = threadIdx.x;
    const int r0 = blockIdx.x * 128;
    const int c0 = blockIdx.y * 128;
    const int ty = tid >> 4, tx = tid & 15;

    float acc[8][8];
#pragma unroll
    for (int i = 0; i < 8; ++i)
#pragma unroll
        for (int j = 0; j < 8; ++j) acc[i][j] = 0.0f;

    for (int kk = 0; kk < K; kk += 32) {
        __syncthreads();
#pragma unroll
        for (int i = 0; i < 4; ++i) {
            int idx = tid + i * 256;          // 1024 float4 slots: 128 rows x 8 kgroups
            int row = idx >> 3, kg = idx & 7;
            int k = kk + kg * 4;
            float4 v = make_float4(0.f, 0.f, 0.f, 0.f);
            if (k < K) v = *(const float4*)&A[(size_t)(r0 + row) * K + k];
            As[(kg * 4 + 0) * LD + row] = v.x;
            As[(kg * 4 + 1) * LD + row] = v.y;
            As[(kg * 4 + 2) * LD + row] = v.z;
            As[(kg * 4 + 3) * LD + row] = v.w;
        }
#pragma unroll
        for (int i = 0; i < 4; ++i) {
            int idx = tid + i * 256;          // 1024 float4 slots: 32 k x 32 colgroups
            int k = idx >> 5, cg = idx & 31;
            int gk = kk + k, gc = c0 + cg * 4;
            float4 v = make_float4(0.f, 0.f, 0.f, 0.f);
            if (gk < K && gc < N) v = *(const float4*)&W[(size_t)gk * N + gc];
            *(float4*)&Ws[k * LD + cg * 4] = v;
        }
        __syncthreads();
#pragma unroll
        for (int k = 0; k < 32; ++k) {
            float4 a0 = *(const float4*)&As[k * LD + ty * 8];
            float4 a1 = *(const float4*)&As[k * LD + ty * 8 + 4];
            float4 b0 = *(const float4*)&Ws[k * LD + tx * 8];
            float4 b1 = *(const float4*)&Ws[k * LD + tx * 8 + 4];
            float av[8] = {a0.x, a0.y, a0.z, a0.w, a1.x, a1.y, a1.z, a1.w};
            float bv[8] = {b0.x, b0.y, b0.z, b0.w, b1.x, b1.y, b1.z, b1.w};
#pragma unroll
            for (int i = 0; i < 8; ++i)
#pragma unroll
                for (int j = 0; j < 8; ++j) acc[i][j] += av[i] * bv[j];
        }
    }

    float bv[8];
#pragma unroll
    for (int j = 0; j < 8; ++j) {
        int c = c0 + tx * 8 + j;
        bv[j] = (c < N) ? bias[c] : 0.0f;
    }
#pragma unroll
    for (int i = 0; i < 8; ++i) {
        int r = r0 + ty * 8 + i;
        size_t orow = SWAP ? ((size_t)(r & 255) * BATCH + (r >> 8)) : (size_t)r;
        int cb = c0 + tx * 8;
        if (cb < N) {
            float4 v = make_float4(acc[i][0] + bv[0], acc[i][1] + bv[1],
                                   acc[i][2] + bv[2], acc[i][3] + bv[3]);
            *(float4*)&out[orow * N + cb] = v;
        }
        if (cb + 4 < N) {
            float4 v = make_float4(acc[i][4] + bv[4], acc[i][5] + bv[5],
                                   acc[i][6] + bv[6], acc[i][7] + bv[7]);
            *(float4*)&out[orow * N + cb + 4] = v;
        }
    }
}

// =================== recurrence, layer 1 ===================
// z = zx[t] (bias included) + h @ U1. Thread k<200 owns cols {k, k+200}
// (i,g for k<100; f,o for k>=100). 200 U-regs. 2 barriers/step.
__global__ __launch_bounds__(256, 2)
void rec1_kernel(const float* __restrict__ zx,   // [T][B][400]
                 const float* __restrict__ U1,   // [100][400]
                 float* __restrict__ h1seq)      // [T][B][100]
{
    const int row = blockIdx.x;
    const int k = threadIdx.x;
    __shared__ __align__(16) float hs[H1];
    __shared__ __align__(8) float fo[2 * H1];

    float u0[H1], u1[H1];
    const int c0 = k, c1 = k + 200;
    if (k < 200) {
#pragma unroll
        for (int j = 0; j < H1; ++j) {
            u0[j] = U1[j * 400 + c0];
            u1[j] = U1[j * 400 + c1];
        }
    }
    if (k < H1) hs[k] = 0.0f;
    float cst = 0.0f;
    float zc0 = 0.f, zc1 = 0.f;
    if (k < 200) {
        zc0 = zx[(size_t)row * 400 + c0];
        zc1 = zx[(size_t)row * 400 + c1];
    }
    __syncthreads();

    for (int t = 0; t < T_SEQ; ++t) {
        int tn = (t + 1 < T_SEQ) ? t + 1 : t;
        float zn0 = 0.f, zn1 = 0.f;
        if (k < 200) {
            const float* p = &zx[((size_t)tn * BATCH + row) * 400];
            zn0 = p[c0];
            zn1 = p[c1];
        }
        float a0 = zc0, a1 = zc1;
        if (k < 200) {
#pragma unroll
            for (int q = 0; q < H1 / 4; ++q) {
                float4 h4 = *(const float4*)&hs[4 * q];
                a0 += h4.x * u0[4 * q] + h4.y * u0[4 * q + 1] + h4.z * u0[4 * q + 2] + h4.w * u0[4 * q + 3];
                a1 += h4.x * u1[4 * q] + h4.y * u1[4 * q + 1] + h4.z * u1[4 * q + 2] + h4.w * u1[4 * q + 3];
            }
            a0 = sigmoidf_(a0);                                   // i or f
            a1 = (k < H1) ? fmaxf(a1, 0.0f) : sigmoidf_(a1);      // g (relu) or o
            if (k >= H1) *(float2*)&fo[2 * (k - H1)] = make_float2(a0, a1);
        }
        __syncthreads();
        if (k < H1) {
            float2 f_o = *(const float2*)&fo[2 * k];
            cst = f_o.x * cst + a0 * a1;          // c = f*c + i*g
            float h = f_o.y * fmaxf(cst, 0.0f);   // h = o*relu(c)
            hs[k] = h;
            h1seq[((size_t)t * BATCH + row) * H1 + k] = h;
        }
        __syncthreads();
        zc0 = zn0;
        zc1 = zn1;
    }
}

// =================== recurrence, layer 2 (time-chunked) ===================
// 4-way k-split: thread (kq=tid>>7, cl=tid&127) accumulates partials over
// k in [kq*32, kq*32+32) for cols {cl, cl+128, cl+256, cl+384}. 128 U-regs.
// State (c,h) carried between chunk launches via cbuf/hbuf.
template<bool INIT, bool LAST>
__global__ __launch_bounds__(512, 2)
void rec2_chunk(const float* __restrict__ zx,    // [tlen][B][512] (bias included)
                const float* __restrict__ U2,    // [128][512]
                float* __restrict__ cbuf,        // [B][128]
                float* __restrict__ hbuf,        // [B][128]
                float* __restrict__ h2out,       // [B][128] (used when LAST)
                int tlen)
{
    const int row = blockIdx.x;
    const int tid = threadIdx.x;   // 0..511
    const int kq = tid >> 7;
    const int cl = tid & 127;
    __shared__ __align__(16) float hs[H2];
    __shared__ float zp[4 * 512];
    __shared__ float za[512];

    float u[4][32];
#pragma unroll
    for (int m = 0; m < 4; ++m)
#pragma unroll
        for (int q = 0; q < 32; ++q)
            u[m][q] = U2[(size_t)(kq * 32 + q) * 512 + cl + 128 * m];

    float cst = 0.0f;
    if (tid < H2) {
        if (INIT) {
            hs[tid] = 0.0f;
        } else {
            hs[tid] = hbuf[(size_t)row * H2 + tid];
            cst = cbuf[(size_t)row * H2 + tid];
        }
    }
    float zc = zx[(size_t)row * 512 + tid];
    __syncthreads();

    for (int t = 0; t < tlen; ++t) {
        int tn = (t + 1 < tlen) ? t + 1 : t;
        float zn = zx[((size_t)tn * BATCH + row) * 512 + tid];

        float acc0 = 0.f, acc1 = 0.f, acc2 = 0.f, acc3 = 0.f;
#pragma unroll
        for (int j = 0; j < 8; ++j) {
            float4 h4 = *(const float4*)&hs[kq * 32 + 4 * j];
            acc0 += h4.x * u[0][4 * j] + h4.y * u[0][4 * j + 1] + h4.z * u[0][4 * j + 2] + h4.w * u[0][4 * j + 3];
            acc1 += h4.x * u[1][4 * j] + h4.y * u[1][4 * j + 1] + h4.z * u[1][4 * j + 2] + h4.w * u[1][4 * j + 3];
            acc2 += h4.x * u[2][4 * j] + h4.y * u[2][4 * j + 1] + h4.z * u[2][4 * j + 2] + h4.w * u[2][4 * j + 3];
            acc3 += h4.x * u[3][4 * j] + h4.y * u[3][4 * j + 1] + h4.z * u[3][4 * j + 2] + h4.w * u[3][4 * j + 3];
        }
        zp[kq * 512 + cl]       = acc0;
        zp[kq * 512 + cl + 128] = acc1;
        zp[kq * 512 + cl + 256] = acc2;
        zp[kq * 512 + cl + 384] = acc3;
        __syncthreads();

        float z = zc + zp[tid] + zp[512 + tid] + zp[1024 + tid] + zp[1536 + tid];
        float a = (tid >= 2 * H2 && tid < 3 * H2) ? fmaxf(z, 0.0f) : sigmoidf_(z);
        za[tid] = a;
        __syncthreads();

        if (tid < H2) {
            float i = za[tid], f = za[tid + 128], g = za[tid + 256], o = za[tid + 384];
            cst = f * cst + i * g;
            hs[tid] = o * fmaxf(cst, 0.0f);
        }
        __syncthreads();
        zc = zn;
    }

    if (tid < H2) {
        float h = hs[tid];
        cbuf[(size_t)row * H2 + tid] = cst;
        hbuf[(size_t)row * H2 + tid] = h;
        if (LAST) h2out[(size_t)row * H2 + tid] = h;
    }
}

// =================== dense + softmax ===================
__global__ __launch_bounds__(64, 1)
void dense_softmax_kernel(const float* __restrict__ h2, const float* __restrict__ Wd,
                          const float* __restrict__ bd, float* __restrict__ out)
{
    const int b = blockIdx.x;
    const int k = threadIdx.x;
    __shared__ __align__(16) float hsm[H2];
    if (k < H2 / 4) ((float4*)hsm)[k] = ((const float4*)(h2 + (size_t)b * H2))[k];
    __syncthreads();

    float logit = -1e30f;
    if (k < NCLS) {
        float acc = bd[k];
#pragma unroll
        for (int d = 0; d < H2; ++d) acc += hsm[d] * Wd[d * NCLS + k];
        logit = acc;
    }
    float m = logit;
#pragma unroll
    for (int off = 32; off >= 1; off >>= 1) m = fmaxf(m, __shfl_xor(m, off, 64));
    float e = (k < NCLS) ? __expf(logit - m) : 0.0f;
    float s = e;
#pragma unroll
    for (int off = 32; off >= 1; off >>= 1) s += __shfl_xor(s, off, 64);
    if (k < NCLS) out[(size_t)b * NCLS + k] = e / s;
}

// =================== round-1 fallback kernels ===================
__global__ __launch_bounds__(448, 1)
void lstm1_fb(const float* __restrict__ x, const float* __restrict__ W1,
              const float* __restrict__ U1, const float* __restrict__ b1,
              float* __restrict__ h1out)
{
    const int b = blockIdx.x;
    const int k = threadIdx.x;
    __shared__ __align__(16) float xs[IN_DIM];
    __shared__ __align__(16) float hs[H1];
    __shared__ __align__(16) float zs[4 * H1];
    float w1r[IN_DIM];
    float u1r[H1];
    float bias = 0.0f;
    if (k < 4 * H1) {
        bias = b1[k];
#pragma unroll
        for (int d = 0; d < IN_DIM; ++d) w1r[d] = W1[d * (4 * H1) + k];
#pragma unroll
        for (int j = 0; j < H1; ++j) u1r[j] = U1[j * (4 * H1) + k];
    }
    if (k < H1) hs[k] = 0.0f;
    if (k < IN_DIM / 4)
        ((float4*)xs)[k] = ((const float4*)(x + ((size_t)b * T_SEQ) * IN_DIM))[k];
    float c = 0.0f;
    __syncthreads();
    for (int t = 0; t < T_SEQ; ++t) {
        if (k < 4 * H1) {
            float acc0 = bias, acc1 = 0.f, acc2 = 0.f, acc3 = 0.f;
#pragma unroll
            for (int q = 0; q < IN_DIM / 4; ++q) {
                float4 xv = ((const float4*)xs)[q];
                acc0 += xv.x * w1r[4 * q]; acc1 += xv.y * w1r[4 * q + 1];
                acc2 += xv.z * w1r[4 * q + 2]; acc3 += xv.w * w1r[4 * q + 3];
            }
#pragma unroll
            for (int q = 0; q < H1 / 4; ++q) {
                float4 hv = ((const float4*)hs)[q];
                acc0 += hv.x * u1r[4 * q]; acc1 += hv.y * u1r[4 * q + 1];
                acc2 += hv.z * u1r[4 * q + 2]; acc3 += hv.w * u1r[4 * q + 3];
            }
            float zv = (acc0 + acc1) + (acc2 + acc3);
            zs[k] = (k >= 2 * H1 && k < 3 * H1) ? fmaxf(zv, 0.0f) : sigmoidf_(zv);
        }
        __syncthreads();
        if (k < H1) {
            float i = zs[k], f = zs[k + H1], g = zs[k + 2 * H1], o = zs[k + 3 * H1];
            c = f * c + i * g;
            float h = o * fmaxf(c, 0.0f);
            hs[k] = h;
            h1out[((size_t)t * BATCH + b) * H1 + k] = h;
        }
        int tn = t + 1;
        if (tn < T_SEQ && k < IN_DIM / 4)
            ((float4*)xs)[k] = ((const float4*)(x + ((size_t)b * T_SEQ + tn) * IN_DIM))[k];
        __syncthreads();
    }
}

__global__ __launch_bounds__(512, 1)
void lstm2_fb(const float* __restrict__ h1in, const float* __restrict__ W2,
              const float* __restrict__ U2, const float* __restrict__ b2,
              float* __restrict__ h2out)
{
    const int b = blockIdx.x;
    const int k = threadIdx.x;
    __shared__ __align__(16) float ps[H1];
    __shared__ __align__(16) float hs[H2];
    __shared__ __align__(16) float zs[4 * H2];
    float w2r[H1];
    float u2r[H2];
    float bias = b2[k];
#pragma unroll
    for (int j = 0; j < H1; ++j) w2r[j] = W2[j * (4 * H2) + k];
#pragma unroll
    for (int j = 0; j < H2; ++j) u2r[j] = U2[j * (4 * H2) + k];
    if (k < H2) hs[k] = 0.0f;
    if (k < H1 / 4)
        ((float4*)ps)[k] = ((const float4*)(h1in + (size_t)b * H1))[k];
    float c = 0.0f;
    float hlast = 0.0f;
    __syncthreads();
    for (int t = 0; t < T_SEQ; ++t) {
        float acc0 = bias, acc1 = 0.f, acc2 = 0.f, acc3 = 0.f;
#pragma unroll
        for (int q = 0; q < H1 / 4; ++q) {
            float4 pv = ((const float4*)ps)[q];
            acc0 += pv.x * w2r[4 * q]; acc1 += pv.y * w2r[4 * q + 1];
            acc2 += pv.z * w2r[4 * q + 2]; acc3 += pv.w * w2r[4 * q + 3];
        }
#pragma unroll
        for (int q = 0; q < H2 / 4; ++q) {
            float4 hv = ((const float4*)hs)[q];
            acc0 += hv.x * u2r[4 * q]; acc1 += hv.y * u2r[4 * q + 1];
            acc2 += hv.z * u2r[4 * q + 2]; acc3 += hv.w * u2r[4 * q + 3];
        }
        float zv = (acc0 + acc1) + (acc2 + acc3);
        zs[k] = (k >= 2 * H2 && k < 3 * H2) ? fmaxf(zv, 0.0f) : sigmoidf_(zv);
        __syncthreads();
        if (k < H2) {
            float i = zs[k], f = zs[k + H2], g = zs[k + 2 * H2], o = zs[k + 3 * H2];
            c = f * c + i * g;
            hlast = o * fmaxf(c, 0.0f);
            hs[k] = hlast;
        }
        int tn = t + 1;
        if (tn < T_SEQ && k < H1 / 4)
            ((float4*)ps)[k] = ((const float4*)(h1in + ((size_t)tn * BATCH + b) * H1))[k];
        __syncthreads();
    }
    if (k < H2) h2out[(size_t)b * H2 + k] = hlast;
}

extern "C" void kernel_launch(void* const* d_in, const int* in_sizes, int n_in,
                              void* d_out, int out_size, void* d_ws, size_t ws_size,
                              hipStream_t stream) {
    const float* x  = (const float*)d_in[0];
    const float* W1 = (const float*)d_in[1];
    const float* U1 = (const float*)d_in[2];
    const float* b1 = (const float*)d_in[3];
    const float* W2 = (const float*)d_in[4];
    const float* U2 = (const float*)d_in[5];
    const float* b2 = (const float*)d_in[6];
    const float* Wd = (const float*)d_in[7];
    const float* bd = (const float*)d_in[8];
    float* out = (float*)d_out;

    const size_t zx_elems = (size_t)T_SEQ * BATCH * 400;   // 52428800 (zx1; zx2 chunk needs half)
    const size_t h1_elems = (size_t)T_SEQ * BATCH * H1;    // 13107200
    const size_t st_elems = (size_t)BATCH * H2;            // 65536
    const size_t need = (zx_elems + h1_elems + 3 * st_elems) * sizeof(float);  // 262.93 MB

    if (ws_size >= need) {
        float* zxbuf = (float*)d_ws;
        float* h1buf = zxbuf + zx_elems;
        float* cbuf  = h1buf + h1_elems;
        float* hbuf  = cbuf + st_elems;
        float* h2buf = hbuf + st_elems;
        const int TC = T_SEQ / 2;   // 128-step chunks

        // zx1 = x @ W1 + b1 -> [T][B][400]
        hipLaunchKernelGGL((proj_kernel<IN_DIM, 4 * H1, true>), dim3(1024, 4), dim3(256), 0, stream,
                           x, W1, b1, zxbuf);
        hipLaunchKernelGGL(rec1_kernel, dim3(BATCH), dim3(256), 0, stream,
                           zxbuf, U1, h1buf);
        // ---- layer 2, chunk A (t = 0..127): zx2 chunk overwrites zx1 region ----
        hipLaunchKernelGGL((proj_kernel<H1, 4 * H2, false>), dim3(512, 4), dim3(256), 0, stream,
                           h1buf, W2, b2, zxbuf);
        hipLaunchKernelGGL((rec2_chunk<true, false>), dim3(BATCH), dim3(512), 0, stream,
                           zxbuf, U2, cbuf, hbuf, h2buf, TC);
        // ---- layer 2, chunk B (t = 128..255) ----
        hipLaunchKernelGGL((proj_kernel<H1, 4 * H2, false>), dim3(512, 4), dim3(256), 0, stream,
                           h1buf + (size_t)TC * BATCH * H1, W2, b2, zxbuf);
        hipLaunchKernelGGL((rec2_chunk<false, true>), dim3(BATCH), dim3(512), 0, stream,
                           zxbuf, U2, cbuf, hbuf, h2buf, TC);

        hipLaunchKernelGGL(dense_softmax_kernel, dim3(BATCH), dim3(64), 0, stream,
                           h2buf, Wd, bd, out);
    } else {
        // fallback: round-1 fused kernels (needs ~52.7 MB)
        float* h1buf = (float*)d_ws;
        float* h2buf = h1buf + h1_elems;
        hipLaunchKernelGGL(lstm1_fb, dim3(BATCH), dim3(448), 0, stream, x, W1, U1, b1, h1buf);
        hipLaunchKernelGGL(lstm2_fb, dim3(BATCH), dim3(512), 0, stream, h1buf, W2, U2, b2, h2buf);
        hipLaunchKernelGGL(dense_softmax_kernel, dim3(BATCH), dim3(64), 0, stream, h2buf, Wd, bd, out);
    }
}